// Round 4
// baseline (1285.226 us; speedup 1.0000x reference)
//
#include <hip/hip_runtime.h>
#include <hip/hip_bf16.h>

typedef unsigned short ushort_t;
typedef __attribute__((ext_vector_type(8))) short short8;   // 8 bf16 = 4 VGPRs
typedef __attribute__((ext_vector_type(4))) float f32x4;    // MFMA C/D
typedef __attribute__((ext_vector_type(2))) float f32x2;    // packed VALU pair

#define N_NODES 20000
#define N_EDGES 320000
#define F_NODE 64
#define F_EDGE 16
#define HID 300
#define HP 300          // h row stride
#define NTILES 20       // wfrag n-tiles; tile 19 pure pad
#define DEPTH 3
#define N_GRAPHS 128
#define KE2N 384        // e2n K: 64 (x) + 300 (S) + 20 pad
#define ATS 328         // LDS A-tile row stride (ushorts)

#define WFRAG_USHORT_PER_LAYER (10 * NTILES * 64 * 8)  // 102400 ushorts
#define W2FRAG_USHORT (NTILES * 64 * 8)                // 10240 ushorts (1 K-chunk)
#define WE2NFRAG_USHORT (12 * NTILES * 64 * 8)         // 122880 ushorts

__device__ __forceinline__ float bf2f(ushort_t u) {
    union { unsigned int i; float f; } v;
    v.i = ((unsigned int)u) << 16;
    return v.f;
}

// two packed bf16 (lo,hi of a u32) -> f32x2
__device__ __forceinline__ f32x2 bfpair(unsigned int u) {
    union { unsigned int i[2]; f32x2 f; } v;
    v.i[0] = u << 16;
    v.i[1] = u & 0xffff0000u;
    return v.f;
}

__device__ __forceinline__ f32x2 pmax0(f32x2 a) {
#if __has_builtin(__builtin_elementwise_max)
    f32x2 z = {0.f, 0.f};
    return __builtin_elementwise_max(a, z);
#else
    f32x2 r; r.x = fmaxf(a.x, 0.f); r.y = fmaxf(a.y, 0.f); return r;
#endif
}

__device__ __forceinline__ unsigned int fpack(float lo, float hi) {
#if __has_builtin(__builtin_amdgcn_cvt_pk_bf16_f32)
    auto r = __builtin_amdgcn_cvt_pk_bf16_f32(lo, hi);
    union { decltype(r) b; unsigned int u; } v;
    v.b = r;
    return v.u;
#else
    union { float f; unsigned int i; } a, b;
    a.f = lo; b.f = hi;
    return ((a.i + 0x8000u) >> 16) | ((b.i + 0x8000u) & 0xffff0000u);
#endif
}
__device__ __forceinline__ unsigned int fpack2(f32x2 a) { return fpack(a.x, a.y); }
__device__ __forceinline__ ushort_t f2bf(float f) {
    return (ushort_t)(fpack(f, 0.f) & 0xffffu);
}

// ---------------- CSR build ----------------
__global__ __launch_bounds__(256) void csr_hist(
    const int* __restrict__ col, int* __restrict__ deg)
{
    int e = blockIdx.x * 256 + threadIdx.x;
    atomicAdd(&deg[col[e]], 1);
}

__global__ __launch_bounds__(256) void csr_scan(
    const int* __restrict__ deg, int* __restrict__ offsets,
    int* __restrict__ cursor)
{
    __shared__ int sums[256];
    const int t = threadIdx.x;
    const int CH = 79;
    int base = t * CH;
    int local = 0;
    for (int i = 0; i < CH; ++i) {
        int idx = base + i;
        if (idx < N_NODES) local += deg[idx];
    }
    sums[t] = local;
    __syncthreads();
    for (int off = 1; off < 256; off <<= 1) {
        int v = (t >= off) ? sums[t - off] : 0;
        __syncthreads();
        sums[t] += v;
        __syncthreads();
    }
    int run = (t > 0) ? sums[t - 1] : 0;
    for (int i = 0; i < CH; ++i) {
        int idx = base + i;
        if (idx < N_NODES) {
            offsets[idx] = run;
            cursor[idx] = run;
            run += deg[idx];
        }
    }
}

__global__ __launch_bounds__(256) void csr_fill(
    const int* __restrict__ col, int* __restrict__ cursor,
    int* __restrict__ eid)
{
    int e = blockIdx.x * 256 + threadIdx.x;
    int pos = atomicAdd(&cursor[col[e]], 1);
    eid[pos] = e;
}

__global__ __launch_bounds__(256) void ghist(
    const int* __restrict__ batch, int* __restrict__ gdeg)
{
    int n = blockIdx.x * 256 + threadIdx.x;
    if (n < N_NODES) atomicAdd(&gdeg[batch[n]], 1);
}

__global__ __launch_bounds__(128) void gscan(
    const int* __restrict__ gdeg, int* __restrict__ goff)
{
    __shared__ int s[128];
    int t = threadIdx.x;
    int d = gdeg[t];
    s[t] = d;
    __syncthreads();
    for (int off = 1; off < 128; off <<= 1) {
        int v = (t >= off) ? s[t - off] : 0;
        __syncthreads();
        s[t] += v;
        __syncthreads();
    }
    goff[t] = s[t] - d;
    if (t == 127) goff[128] = s[127];
}

// ---------------- W fragment pre-packs ----------------
__global__ __launch_bounds__(64) void wfrag_build(
    const float* __restrict__ W_convs, ushort_t* __restrict__ wfrag)
{
    const int c = blockIdx.x, t = blockIdx.y, l = blockIdx.z;
    const int lane = threadIdx.x;
    const int k0 = c * 32 + (lane >> 4) * 8;
    const int n  = t * 16 + (lane & 15);
    ushort_t* dst = wfrag + (size_t)l * WFRAG_USHORT_PER_LAYER
                  + ((size_t)(c * NTILES + t) * 64 + lane) * 8;
    const float* Wl = W_convs + (size_t)l * HID * HID;
    #pragma unroll
    for (int j = 0; j < 8; ++j) {
        int k = k0 + j;
        float v = (k < HID && n < HID) ? Wl[(long)k * HID + n] : 0.f;
        dst[j] = f2bf(v);
    }
}

__global__ __launch_bounds__(64) void wfrag2_build(
    const float* __restrict__ W_e2n, ushort_t* __restrict__ wfrag2)
{
    const int c = blockIdx.x, t = blockIdx.y;
    const int lane = threadIdx.x;
    const int k0 = c * 32 + (lane >> 4) * 8;
    const int n  = t * 16 + (lane & 15);
    ushort_t* dst = wfrag2 + ((size_t)(c * NTILES + t) * 64 + lane) * 8;
    #pragma unroll
    for (int j = 0; j < 8; ++j) {
        int k = k0 + j;
        float v = (k < F_NODE + HID && n < HID) ? W_e2n[(long)k * HID + n] : 0.f;
        dst[j] = f2bf(v);
    }
}

// W2 (= W_init rows 64..79) as ONE 16x16x32 B-chunk
__global__ __launch_bounds__(64) void w2frag_build(
    const float* __restrict__ W2, ushort_t* __restrict__ w2frag)
{
    const int t = blockIdx.x;
    const int lane = threadIdx.x;
    const int k0 = (lane >> 4) * 8;
    const int n  = t * 16 + (lane & 15);
    ushort_t* dst = w2frag + ((size_t)t * 64 + lane) * 8;
    #pragma unroll
    for (int j = 0; j < 8; ++j) {
        int k = k0 + j;
        float v = (k < F_EDGE && n < HID) ? W2[(long)k * HID + n] : 0.f;
        dst[j] = f2bf(v);
    }
}

// ---------------- kernels ----------------

// K1: xW1b[n][c] = bf16(b_init[c] + x[n] @ W_init[0:64]);  stride HID
__global__ __launch_bounds__(256) void node_init_gemm(
    const float* __restrict__ x, const float* __restrict__ W_init,
    const float* __restrict__ b_init, ushort_t* __restrict__ xW1b)
{
    __shared__ float xs[16 * 64];
    const int tid = threadIdx.x;
    const long n0 = (long)blockIdx.x * 16;
    for (int i = tid; i < 16 * 64; i += 256) xs[i] = x[n0 * 64 + i];
    __syncthreads();
    const int nl = tid >> 4, ct = tid & 15;
    for (int q = 0; q < 19; ++q) {
        int c = ct + 16 * q;
        if (c < HID) {
            float acc = b_init[c];
            #pragma unroll 8
            for (int k = 0; k < 64; ++k)
                acc = fmaf(xs[nl * 64 + k], W_init[(long)k * HID + c], acc);
            xW1b[(n0 + nl) * HID + c] = f2bf(acc);
        }
    }
}

// Phase-0 helper for 512-thr edge_update: wave quarter-tiles of P = EA @ W2.
__device__ __forceinline__ void p_phase8(
    ushort_t* At, const float* __restrict__ edge_attr,
    const ushort_t* __restrict__ w2frag, long e0,
    int wave, int quad, int m, int lane)
{
    const int mtp = wave >> 2;
    const int nt0p = (wave & 3) * 5;
    short8 a_ea;
    {
        union { uint4 u4; short8 s8; } af;
        if (quad < 2) {
            const float* eap = edge_attr + (e0 + mtp * 16 + m) * 16 + quad * 8;
            float4 v0 = *(const float4*)eap;
            float4 v1 = *(const float4*)(eap + 4);
            af.u4.x = fpack(v0.x, v0.y); af.u4.y = fpack(v0.z, v0.w);
            af.u4.z = fpack(v1.x, v1.y); af.u4.w = fpack(v1.z, v1.w);
        } else {
            af.u4.x = 0; af.u4.y = 0; af.u4.z = 0; af.u4.w = 0;
        }
        a_ea = af.s8;
    }
    #pragma unroll
    for (int t = 0; t < 5; ++t) {
        int nt = nt0p + t;
        if (nt >= 19) continue;   // pad tile
        short8 b = *(const short8*)(w2frag + ((size_t)nt * 64 + lane) * 8);
        int c = nt * 16 + m;
        f32x4 pc = (f32x4){0.f, 0.f, 0.f, 0.f};
        pc = __builtin_amdgcn_mfma_f32_16x16x32_bf16(a_ea, b, pc, 0, 0, 0);
        #pragma unroll
        for (int r = 0; r < 4; ++r)
            At[(mtp * 16 + quad * 4 + r) * ATS + c] = f2bf(pc[r]);
    }
}

// Fused conv layer, 32-edge blocks, 256 thr / 4 waves.
// Latency-bound regime (R1-R3): all pipes <45%, occupancy pinned ~13.7
// waves/CU regardless of geometry. Attack: T14 issue-early/use-late.
//  - phase-1 gather loads (xW1b/Sb/h random 600B rows) issued at kernel
//    ENTRY, 1-deep pipelined across the 5 iterations.
//  - phase-2 b-fragment (global) + a (LDS) loads pipelined 1 c-step ahead.
template<bool UPDATE>
__global__ __launch_bounds__(256) void fused_conv(
    ushort_t* h, const ushort_t* __restrict__ Sb,
    const ushort_t* __restrict__ xW1b, const float* __restrict__ edge_attr,
    const int* __restrict__ row, const ushort_t* __restrict__ w2frag,
    const ushort_t* __restrict__ wfrag_l)
{
    __shared__ ushort_t At[32 * ATS];   // 20992 B
    const int tid = threadIdx.x;
    const int wave = tid >> 6, lane = tid & 63;
    const int quad = lane >> 4, m = lane & 15;
    const long e0 = (long)blockIdx.x * 32;

    // phase-1 load issue: iteration k covers i = tid + 256k of 16x80 cells
    auto issue = [&](int k, uint2& xa, uint2& xb, uint2& wa, uint2& wb,
                     uint2& sa, uint2& sb, int& la, int& lb, int& g) {
        int i = tid + (k << 8);
        int p = i / 80; g = i % 80;
        la = 2 * p; lb = la + 1;
        if (g < 75) {
            int c0 = 4 * g;
            int ra = row[e0 + la], rb = row[e0 + lb];
            xa = *(const uint2*)&xW1b[(long)ra * HID + c0];
            xb = *(const uint2*)&xW1b[(long)rb * HID + c0];
            if (UPDATE) {
                wa = *(const uint2*)&h[(e0 + la) * HP + c0];
                wb = *(const uint2*)&h[(e0 + lb) * HP + c0];
                sa = *(const uint2*)&Sb[(long)ra * HID + c0];
                sb = *(const uint2*)&Sb[(long)rb * HID + c0];
            }
        }
    };

    uint2 xa0, xb0, wa0, wb0, sa0, sb0;
    int la0, lb0, g0;
    issue(0, xa0, xb0, wa0, wb0, sa0, sb0, la0, lb0, g0);   // EARLY

    // ---- phase 0: P = EA @ W2 (hides the k=0 gather latency) ----
    {
        short8 a_ea[2];
        #pragma unroll
        for (int mt = 0; mt < 2; ++mt) {
            union { uint4 u4; short8 s8; } af;
            if (quad < 2) {
                const float* eap = edge_attr + (e0 + mt * 16 + m) * 16 + quad * 8;
                float4 v0 = *(const float4*)eap;
                float4 v1 = *(const float4*)(eap + 4);
                af.u4.x = fpack(v0.x, v0.y); af.u4.y = fpack(v0.z, v0.w);
                af.u4.z = fpack(v1.x, v1.y); af.u4.w = fpack(v1.z, v1.w);
            } else {
                af.u4.x = 0; af.u4.y = 0; af.u4.z = 0; af.u4.w = 0;
            }
            a_ea[mt] = af.s8;
        }
        const int nt0 = wave * 5;
        #pragma unroll
        for (int t = 0; t < 5; ++t) {
            short8 b = *(const short8*)(w2frag + ((size_t)(nt0 + t) * 64 + lane) * 8);
            int c = (nt0 + t) * 16 + m;
            #pragma unroll
            for (int mt = 0; mt < 2; ++mt) {
                f32x4 pc = (f32x4){0.f, 0.f, 0.f, 0.f};
                pc = __builtin_amdgcn_mfma_f32_16x16x32_bf16(a_ea[mt], b, pc, 0, 0, 0);
                #pragma unroll
                for (int r = 0; r < 4; ++r)
                    At[(mt * 16 + quad * 4 + r) * ATS + c] = f2bf(pc[r]);
            }
        }
    }
    __syncthreads();   // P complete

    // ---- phase 1: 1-deep pipelined edge update into At ----
    #pragma unroll
    for (int k = 0; k < 5; ++k) {
        uint2 xa1, xb1, wa1, wb1, sa1, sb1;
        int la1 = 0, lb1 = 0, g1 = 0;
        if (k < 4)
            issue(k + 1, xa1, xb1, wa1, wb1, sa1, sb1, la1, lb1, g1);
        int c0 = 4 * g0;
        uint2 oa, ob;
        if (g0 < 75) {
            uint2 pa = *(const uint2*)&At[la0 * ATS + c0];
            uint2 pb = *(const uint2*)&At[lb0 * ATS + c0];
            f32x2 h0a0 = pmax0(bfpair(xa0.x) + bfpair(pa.x));
            f32x2 h0a1 = pmax0(bfpair(xa0.y) + bfpair(pa.y));
            f32x2 h0b0 = pmax0(bfpair(xb0.x) + bfpair(pb.x));
            f32x2 h0b1 = pmax0(bfpair(xb0.y) + bfpair(pb.y));
            if (UPDATE) {
                oa.x = fpack2(pmax0(bfpair(sa0.x) - bfpair(wb0.x) + h0a0));
                oa.y = fpack2(pmax0(bfpair(sa0.y) - bfpair(wb0.y) + h0a1));
                ob.x = fpack2(pmax0(bfpair(sb0.x) - bfpair(wa0.x) + h0b0));
                ob.y = fpack2(pmax0(bfpair(sb0.y) - bfpair(wa0.y) + h0b1));
            } else {
                oa.x = fpack2(h0a0); oa.y = fpack2(h0a1);
                ob.x = fpack2(h0b0); ob.y = fpack2(h0b1);
            }
        } else {
            oa.x = 0; oa.y = 0;   // K-pad cols 300..319
            ob = oa;
        }
        *(uint2*)&At[la0 * ATS + c0] = oa;
        *(uint2*)&At[lb0 * ATS + c0] = ob;
        if (k < 4) {
            xa0 = xa1; xb0 = xb1; wa0 = wa1; wb0 = wb1;
            sa0 = sa1; sb0 = sb1; la0 = la1; lb0 = lb1; g0 = g1;
        }
    }
    __syncthreads();   // A tile complete; all h reads done

    // ---- phase 2: main MFMA, b/a loads pipelined 1 c-step ahead ----
    const int nt0 = wave * 5;
    f32x4 acc[5][2];
    #pragma unroll
    for (int t = 0; t < 5; ++t)
        #pragma unroll
        for (int mt = 0; mt < 2; ++mt)
            acc[t][mt] = (f32x4){0.f, 0.f, 0.f, 0.f};

    short8 bc[5], ac[2];
    #pragma unroll
    for (int t = 0; t < 5; ++t)
        bc[t] = *(const short8*)(wfrag_l + ((size_t)(nt0 + t) * 64 + lane) * 8);
    #pragma unroll
    for (int mt = 0; mt < 2; ++mt)
        ac[mt] = *(const short8*)&At[(mt * 16 + m) * ATS + quad * 8];

    #pragma unroll
    for (int c = 0; c < 10; ++c) {
        short8 bn[5], an[2];
        if (c < 9) {
            #pragma unroll
            for (int t = 0; t < 5; ++t)
                bn[t] = *(const short8*)(wfrag_l
                    + ((size_t)((c + 1) * NTILES + nt0 + t) * 64 + lane) * 8);
            #pragma unroll
            for (int mt = 0; mt < 2; ++mt)
                an[mt] = *(const short8*)&At[(mt * 16 + m) * ATS
                    + (c + 1) * 32 + quad * 8];
        }
        #pragma unroll
        for (int t = 0; t < 5; ++t)
            #pragma unroll
            for (int mt = 0; mt < 2; ++mt)
                acc[t][mt] = __builtin_amdgcn_mfma_f32_16x16x32_bf16(
                    ac[mt], bc[t], acc[t][mt], 0, 0, 0);
        if (c < 9) {
            #pragma unroll
            for (int t = 0; t < 5; ++t) bc[t] = bn[t];
            ac[0] = an[0]; ac[1] = an[1];
        }
    }
    #pragma unroll
    for (int t = 0; t < 5; ++t) {
        int col = (nt0 + t) * 16 + m;
        if (col >= HID) continue;
        #pragma unroll
        for (int mt = 0; mt < 2; ++mt) {
            long rbase = (e0 + mt * 16 + quad * 4) * HP + col;
            #pragma unroll
            for (int r = 0; r < 4; ++r)
                h[rbase + (long)r * HP] = f2bf(acc[t][mt][r]);
        }
    }
}

// Final edge update: 32 edges/blk, 512 thr / 8 waves, issue-early pipeline.
__global__ __launch_bounds__(512) void edge_update_mfma(
    ushort_t* h, const ushort_t* __restrict__ Sb,
    const ushort_t* __restrict__ xW1b, const float* __restrict__ edge_attr,
    const int* __restrict__ row, const ushort_t* __restrict__ w2frag)
{
    __shared__ ushort_t Pt[32 * ATS];
    const int tid = threadIdx.x;
    const int wave = tid >> 6, lane = tid & 63;
    const int quad = lane >> 4, m = lane & 15;
    const long e0 = (long)blockIdx.x * 32;

    auto issue = [&](int k, uint2& xa, uint2& xb, uint2& wa, uint2& wb,
                     uint2& sa, uint2& sb, int& la, int& lb, int& g, bool& v) {
        int i = tid + (k << 9);
        v = i < 16 * 75;
        if (v) {
            int p = i / 75; g = i % 75;
            la = 2 * p; lb = la + 1;
            int c0 = 4 * g;
            int ra = row[e0 + la], rb = row[e0 + lb];
            xa = *(const uint2*)&xW1b[(long)ra * HID + c0];
            xb = *(const uint2*)&xW1b[(long)rb * HID + c0];
            wa = *(const uint2*)&h[(e0 + la) * HP + c0];
            wb = *(const uint2*)&h[(e0 + lb) * HP + c0];
            sa = *(const uint2*)&Sb[(long)ra * HID + c0];
            sb = *(const uint2*)&Sb[(long)rb * HID + c0];
        }
    };

    uint2 xa0, xb0, wa0, wb0, sa0, sb0;
    int la0 = 0, lb0 = 0, g0 = 0; bool v0 = false;
    issue(0, xa0, xb0, wa0, wb0, sa0, sb0, la0, lb0, g0, v0);   // EARLY

    p_phase8(Pt, edge_attr, w2frag, e0, wave, quad, m, lane);
    __syncthreads();

    #pragma unroll
    for (int k = 0; k < 3; ++k) {
        uint2 xa1, xb1, wa1, wb1, sa1, sb1;
        int la1 = 0, lb1 = 0, g1 = 0; bool v1 = false;
        if (k < 2)
            issue(k + 1, xa1, xb1, wa1, wb1, sa1, sb1, la1, lb1, g1, v1);
        if (v0) {
            int c0 = 4 * g0;
            uint2 pa = *(const uint2*)&Pt[la0 * ATS + c0];
            uint2 pb = *(const uint2*)&Pt[lb0 * ATS + c0];
            f32x2 h0a0 = pmax0(bfpair(xa0.x) + bfpair(pa.x));
            f32x2 h0a1 = pmax0(bfpair(xa0.y) + bfpair(pa.y));
            f32x2 h0b0 = pmax0(bfpair(xb0.x) + bfpair(pb.x));
            f32x2 h0b1 = pmax0(bfpair(xb0.y) + bfpair(pb.y));
            uint2 oa, ob;
            oa.x = fpack2(pmax0(bfpair(sa0.x) - bfpair(wb0.x) + h0a0));
            oa.y = fpack2(pmax0(bfpair(sa0.y) - bfpair(wb0.y) + h0a1));
            ob.x = fpack2(pmax0(bfpair(sb0.x) - bfpair(wa0.x) + h0b0));
            ob.y = fpack2(pmax0(bfpair(sb0.y) - bfpair(wa0.y) + h0b1));
            *(uint2*)&h[(e0 + la0) * HP + c0] = oa;
            *(uint2*)&h[(e0 + lb0) * HP + c0] = ob;
        }
        if (k < 2) {
            xa0 = xa1; xb0 = xb1; wa0 = wa1; wb0 = wb1;
            sa0 = sa1; sb0 = sb1; la0 = la1; lb0 = lb1; g0 = g1; v0 = v1;
        }
    }
}

// K4: Sb[n][:] = bf16( bias[:] + segsum );  stride HID. 4-deep MLP.
__global__ __launch_bounds__(256) void gather_sum(
    const ushort_t* __restrict__ src, const int* __restrict__ offsets,
    const int* __restrict__ ends, const int* __restrict__ eid,
    const float* __restrict__ bias, ushort_t* __restrict__ Sb)
{
    long idx = (long)blockIdx.x * 256 + threadIdx.x;
    if (idx >= (long)N_NODES * 75) return;
    int n = (int)(idx / 75);
    int g = (int)(idx % 75);
    int beg = offsets[n], end = ends[n];
    f32x2 A0 = {0.f, 0.f}, A1 = {0.f, 0.f};
    f32x2 B0 = {0.f, 0.f}, B1 = {0.f, 0.f};
    f32x2 C0 = {0.f, 0.f}, C1 = {0.f, 0.f};
    f32x2 D0 = {0.f, 0.f}, D1 = {0.f, 0.f};
    int j = beg;
    for (; j + 3 < end; j += 4) {
        int ea = eid[j], eb = eid[j + 1], ec = eid[j + 2], ed = eid[j + 3];
        uint2 va = ((const uint2*)src)[(long)ea * (HP / 4) + g];
        uint2 vb = ((const uint2*)src)[(long)eb * (HP / 4) + g];
        uint2 vc = ((const uint2*)src)[(long)ec * (HP / 4) + g];
        uint2 vd = ((const uint2*)src)[(long)ed * (HP / 4) + g];
        A0 += bfpair(va.x); A1 += bfpair(va.y);
        B0 += bfpair(vb.x); B1 += bfpair(vb.y);
        C0 += bfpair(vc.x); C1 += bfpair(vc.y);
        D0 += bfpair(vd.x); D1 += bfpair(vd.y);
    }
    for (; j < end; ++j) {
        int ea = eid[j];
        uint2 va = ((const uint2*)src)[(long)ea * (HP / 4) + g];
        A0 += bfpair(va.x); A1 += bfpair(va.y);
    }
    float4 bv = *(const float4*)&bias[4 * g];
    f32x2 bv0 = {bv.x, bv.y}, bv1 = {bv.z, bv.w};
    uint2 o;
    o.x = fpack2((A0 + B0) + (C0 + D0) + bv0);
    o.y = fpack2((A1 + B1) + (C1 + D1) + bv1);
    *(uint2*)&Sb[(long)n * HID + 4 * g] = o;
}

// K4b: final gather -> bf16 into Ab cols 64..363. 4-deep MLP.
__global__ __launch_bounds__(256) void gather_ab(
    const ushort_t* __restrict__ src, const int* __restrict__ offsets,
    const int* __restrict__ ends, const int* __restrict__ eid,
    ushort_t* __restrict__ Ab)
{
    long idx = (long)blockIdx.x * 256 + threadIdx.x;
    if (idx >= (long)N_NODES * 75) return;
    int n = (int)(idx / 75);
    int g = (int)(idx % 75);
    int beg = offsets[n], end = ends[n];
    f32x2 A0 = {0.f, 0.f}, A1 = {0.f, 0.f};
    f32x2 B0 = {0.f, 0.f}, B1 = {0.f, 0.f};
    f32x2 C0 = {0.f, 0.f}, C1 = {0.f, 0.f};
    f32x2 D0 = {0.f, 0.f}, D1 = {0.f, 0.f};
    int j = beg;
    for (; j + 3 < end; j += 4) {
        int ea = eid[j], eb = eid[j + 1], ec = eid[j + 2], ed = eid[j + 3];
        uint2 va = ((const uint2*)src)[(long)ea * (HP / 4) + g];
        uint2 vb = ((const uint2*)src)[(long)eb * (HP / 4) + g];
        uint2 vc = ((const uint2*)src)[(long)ec * (HP / 4) + g];
        uint2 vd = ((const uint2*)src)[(long)ed * (HP / 4) + g];
        A0 += bfpair(va.x); A1 += bfpair(va.y);
        B0 += bfpair(vb.x); B1 += bfpair(vb.y);
        C0 += bfpair(vc.x); C1 += bfpair(vc.y);
        D0 += bfpair(vd.x); D1 += bfpair(vd.y);
    }
    for (; j < end; ++j) {
        int ea = eid[j];
        uint2 va = ((const uint2*)src)[(long)ea * (HP / 4) + g];
        A0 += bfpair(va.x); A1 += bfpair(va.y);
    }
    uint2 o;
    o.x = fpack2((A0 + B0) + (C0 + D0));
    o.y = fpack2((A1 + B1) + (C1 + D1));
    *(uint2*)&Ab[(long)n * KE2N + 64 + 4 * g] = o;
}

__global__ __launch_bounds__(256) void x_fill(
    const float* __restrict__ x, ushort_t* __restrict__ Ab)
{
    long idx = (long)blockIdx.x * 256 + threadIdx.x;
    if (idx >= (long)N_NODES * 21) return;
    int n = (int)(idx / 21);
    int q = (int)(idx % 21);
    if (q < 16) {
        float4 v = *(const float4*)&x[(long)n * 64 + 4 * q];
        uint2 o;
        o.x = fpack(v.x, v.y);
        o.y = fpack(v.z, v.w);
        *(uint2*)&Ab[(long)n * KE2N + 4 * q] = o;
    } else {
        uint2 o; o.x = 0; o.y = 0;
        *(uint2*)&Ab[(long)n * KE2N + 364 + 4 * (q - 16)] = o;
    }
}

// K7: hn = relu(Ab @ W_e2n + b)
__global__ __launch_bounds__(256) void e2n_mfma(
    const ushort_t* __restrict__ Ab, const ushort_t* __restrict__ wfrag2,
    const float* __restrict__ b_e2n, float* __restrict__ hn)
{
    const int tid = threadIdx.x;
    const int wave = tid >> 6, lane = tid & 63;
    const int quad = lane >> 4, m = lane & 15;
    const long n0 = (long)blockIdx.x * 64;
    const int nt0 = wave * 5;

    f32x4 acc[5][4];
    #pragma unroll
    for (int t = 0; t < 5; ++t)
        #pragma unroll
        for (int mt = 0; mt < 4; ++mt)
            acc[t][mt] = (f32x4){0.f, 0.f, 0.f, 0.f};

    for (int c = 0; c < 12; ++c) {
        short8 a[4];
        #pragma unroll
        for (int mt = 0; mt < 4; ++mt) {
            long r = n0 + mt * 16 + m;
            if (r > N_NODES - 1) r = N_NODES - 1;
            a[mt] = *(const short8*)(Ab + r * KE2N + c * 32 + quad * 8);
        }
        #pragma unroll
        for (int t = 0; t < 5; ++t) {
            short8 b = *(const short8*)(wfrag2
                + ((size_t)(c * NTILES + nt0 + t) * 64 + lane) * 8);
            #pragma unroll
            for (int mt = 0; mt < 4; ++mt)
                acc[t][mt] = __builtin_amdgcn_mfma_f32_16x16x32_bf16(
                    a[mt], b, acc[t][mt], 0, 0, 0);
        }
    }

    #pragma unroll
    for (int t = 0; t < 5; ++t) {
        int col = (nt0 + t) * 16 + m;
        if (col >= HID) continue;
        float bias = b_e2n[col];
        #pragma unroll
        for (int mt = 0; mt < 4; ++mt) {
            long rw = n0 + mt * 16 + quad * 4;
            #pragma unroll
            for (int r = 0; r < 4; ++r) {
                long rowi = rw + r;
                if (rowi < N_NODES)
                    hn[rowi * HP + col] = fmaxf(acc[t][mt][r] + bias, 0.f);
            }
        }
    }
}

__global__ __launch_bounds__(256) void pool_graph(
    const float* __restrict__ hn, const int* __restrict__ goff,
    float* __restrict__ pooled)
{
    int g = blockIdx.x;
    int beg = goff[g], end = goff[g + 1];
    for (int c = threadIdx.x; c < HID; c += 256) {
        float acc = 0.f;
        for (int n = beg; n < end; ++n)
            acc += hn[(long)n * HP + c];
        pooled[(long)g * HID + c] = acc;
    }
}

__global__ __launch_bounds__(64) void ffn_out(
    const float* __restrict__ pooled, const float* __restrict__ W_ffn,
    const float* __restrict__ b_ffn, float* __restrict__ out)
{
    int g = blockIdx.x;
    int lane = threadIdx.x;
    float s = 0.f;
    for (int c = lane; c < HID; c += 64)
        s += pooled[(long)g * HID + c] * W_ffn[c];
    #pragma unroll
    for (int off = 32; off > 0; off >>= 1)
        s += __shfl_down(s, off, 64);
    if (lane == 0) out[g] = s + b_ffn[0];
}

extern "C" void kernel_launch(void* const* d_in, const int* in_sizes, int n_in,
                              void* d_out, int out_size, void* d_ws, size_t ws_size,
                              hipStream_t stream) {
    const float* x         = (const float*)d_in[0];
    const float* edge_attr = (const float*)d_in[1];
    const int*   edge_index= (const int*)d_in[2];
    const int*   batch     = (const int*)d_in[3];
    const float* W_init    = (const float*)d_in[4];
    const float* b_init    = (const float*)d_in[5];
    const float* W_convs   = (const float*)d_in[6];
    const float* b_convs   = (const float*)d_in[7];
    const float* W_e2n     = (const float*)d_in[8];
    const float* b_e2n     = (const float*)d_in[9];
    const float* W_ffn     = (const float*)d_in[10];
    const float* b_ffn     = (const float*)d_in[11];
    float* out = (float*)d_out;

    const int* row = edge_index;
    const int* col = edge_index + N_EDGES;
    const float* W2 = W_init + (size_t)F_NODE * HID;

    // Workspace (~225 MB)
    const size_t need = (size_t)N_EDGES * HP * 2
                      + (size_t)N_NODES * HID * 2
                      + (size_t)N_NODES * KE2N * 2
                      + (size_t)N_GRAPHS * HID * 4
                      + (size_t)N_NODES * 4 * 2 + (size_t)N_EDGES * 4
                      + (size_t)DEPTH * WFRAG_USHORT_PER_LAYER * 2
                      + (size_t)WE2NFRAG_USHORT * 2
                      + (size_t)W2FRAG_USHORT * 2
                      + (size_t)(N_GRAPHS + 1 + N_GRAPHS) * 4 + 32768;
    if (ws_size < need) return;

    char* p = (char*)d_ws;
    auto take = [&](size_t bytes) {
        char* q = p;
        p += (bytes + 255) & ~(size_t)255;
        return q;
    };
    ushort_t* h       = (ushort_t*)take((size_t)N_EDGES * HP * 2);
    ushort_t* Sb      = (ushort_t*)take((size_t)N_NODES * HID * 2);
    ushort_t* Ab      = (ushort_t*)take((size_t)N_NODES * KE2N * 2);
    float*    pooled  = (float*)take((size_t)N_GRAPHS * HID * 4);
    int*      cursor  = (int*)take((size_t)N_NODES * 4);
    int*      offsets = (int*)take((size_t)N_NODES * 4);
    int*      eid     = (int*)take((size_t)N_EDGES * 4);
    ushort_t* wfrag   = (ushort_t*)take((size_t)DEPTH * WFRAG_USHORT_PER_LAYER * 2);
    ushort_t* wfrag2  = (ushort_t*)take((size_t)WE2NFRAG_USHORT * 2);
    ushort_t* w2frag  = (ushort_t*)take((size_t)W2FRAG_USHORT * 2);
    int*      gdeg    = (int*)take((size_t)N_GRAPHS * 4);
    int*      goff    = (int*)take((size_t)(N_GRAPHS + 1) * 4);

    ushort_t* xW1b = Ab;        // alias: xW1b dead before x_fill writes Ab
    float*    hn   = (float*)h; // alias: h dead after gather_ab

    // CSR + graph-offset build
    hipMemsetAsync(cursor, 0, (size_t)N_NODES * 4, stream);
    hipMemsetAsync(gdeg, 0, (size_t)N_GRAPHS * 4, stream);
    csr_hist<<<N_EDGES / 256, 256, 0, stream>>>(col, cursor);
    csr_scan<<<1, 256, 0, stream>>>(cursor, offsets, cursor);
    csr_fill<<<N_EDGES / 256, 256, 0, stream>>>(col, cursor, eid);
    ghist<<<(N_NODES + 255) / 256, 256, 0, stream>>>(batch, gdeg);
    gscan<<<1, 128, 0, stream>>>(gdeg, goff);

    wfrag_build<<<dim3(10, NTILES, DEPTH), 64, 0, stream>>>(W_convs, wfrag);
    wfrag2_build<<<dim3(12, NTILES, 1), 64, 0, stream>>>(W_e2n, wfrag2);
    w2frag_build<<<NTILES, 64, 0, stream>>>(W2, w2frag);

    node_init_gemm<<<N_NODES / 16, 256, 0, stream>>>(x, W_init, b_init, xW1b);

    const int GS_GRID = ((N_NODES * 75) + 255) / 256;

    // layer 0
    fused_conv<false><<<N_EDGES / 32, 256, 0, stream>>>(
        h, Sb, xW1b, edge_attr, row, w2frag, wfrag);
    gather_sum<<<GS_GRID, 256, 0, stream>>>(
        h, offsets, cursor, eid, b_convs + 0 * HID, Sb);
    // layers 1,2
    fused_conv<true><<<N_EDGES / 32, 256, 0, stream>>>(
        h, Sb, xW1b, edge_attr, row, w2frag,
        wfrag + 1 * (size_t)WFRAG_USHORT_PER_LAYER);
    gather_sum<<<GS_GRID, 256, 0, stream>>>(
        h, offsets, cursor, eid, b_convs + 1 * HID, Sb);
    fused_conv<true><<<N_EDGES / 32, 256, 0, stream>>>(
        h, Sb, xW1b, edge_attr, row, w2frag,
        wfrag + 2 * (size_t)WFRAG_USHORT_PER_LAYER);
    gather_sum<<<GS_GRID, 256, 0, stream>>>(
        h, offsets, cursor, eid, b_convs + 2 * HID, Sb);
    // final update
    edge_update_mfma<<<N_EDGES / 32, 512, 0, stream>>>(
        h, Sb, xW1b, edge_attr, row, w2frag);

    // ---- e2n path ----
    x_fill<<<((N_NODES * 21) + 255) / 256, 256, 0, stream>>>(x, Ab);
    gather_ab<<<GS_GRID, 256, 0, stream>>>(h, offsets, cursor, eid, Ab);
    e2n_mfma<<<(N_NODES + 63) / 64, 256, 0, stream>>>(Ab, wfrag2, b_e2n, hn);
    pool_graph<<<N_GRAPHS, 256, 0, stream>>>(hn, goff, pooled);
    ffn_out<<<N_GRAPHS, 64, 0, stream>>>(pooled, W_ffn, b_ffn, out);
}

// Round 5
// 1210.859 us; speedup vs baseline: 1.0614x; 1.0614x over previous
//
#include <hip/hip_runtime.h>
#include <hip/hip_bf16.h>

typedef unsigned short ushort_t;
typedef __attribute__((ext_vector_type(8))) short short8;   // 8 bf16 = 4 VGPRs
typedef __attribute__((ext_vector_type(4))) float f32x4;    // MFMA C/D
typedef __attribute__((ext_vector_type(2))) float f32x2;    // packed VALU pair

#define N_NODES 20000
#define N_EDGES 320000
#define F_NODE 64
#define F_EDGE 16
#define HID 300
#define HP 300          // h row stride
#define NTILES 20       // wfrag n-tiles; tile 19 pure pad
#define DEPTH 3
#define N_GRAPHS 128
#define KE2N 384        // e2n K: 64 (x) + 300 (S) + 20 pad
// LDS A-tile row stride: 344 ushorts = 172 dwords == 12 (mod 32) banks.
// Old 328 (164 dw == 4 mod 32) gave ~8-way bank conflicts on phase-2
// ds_read_b128 (lane starts 4(m+q)%32 -> 8 starts x 8 lanes); 172%32=12
// gives 12m+4q%32 -> each start shared by exactly 2 lanes (2-way = free).
#define ATS 344

#define WFRAG_USHORT_PER_LAYER (10 * NTILES * 64 * 8)  // 102400 ushorts
#define W2FRAG_USHORT (NTILES * 64 * 8)                // 10240 ushorts (1 K-chunk)
#define WE2NFRAG_USHORT (12 * NTILES * 64 * 8)         // 122880 ushorts

__device__ __forceinline__ float bf2f(ushort_t u) {
    union { unsigned int i; float f; } v;
    v.i = ((unsigned int)u) << 16;
    return v.f;
}

// two packed bf16 (lo,hi of a u32) -> f32x2
__device__ __forceinline__ f32x2 bfpair(unsigned int u) {
    union { unsigned int i[2]; f32x2 f; } v;
    v.i[0] = u << 16;
    v.i[1] = u & 0xffff0000u;
    return v.f;
}

__device__ __forceinline__ f32x2 pmax0(f32x2 a) {
#if __has_builtin(__builtin_elementwise_max)
    f32x2 z = {0.f, 0.f};
    return __builtin_elementwise_max(a, z);
#else
    f32x2 r; r.x = fmaxf(a.x, 0.f); r.y = fmaxf(a.y, 0.f); return r;
#endif
}

__device__ __forceinline__ unsigned int fpack(float lo, float hi) {
#if __has_builtin(__builtin_amdgcn_cvt_pk_bf16_f32)
    auto r = __builtin_amdgcn_cvt_pk_bf16_f32(lo, hi);
    union { decltype(r) b; unsigned int u; } v;
    v.b = r;
    return v.u;
#else
    union { float f; unsigned int i; } a, b;
    a.f = lo; b.f = hi;
    return ((a.i + 0x8000u) >> 16) | ((b.i + 0x8000u) & 0xffff0000u);
#endif
}
__device__ __forceinline__ unsigned int fpack2(f32x2 a) { return fpack(a.x, a.y); }
__device__ __forceinline__ ushort_t f2bf(float f) {
    return (ushort_t)(fpack(f, 0.f) & 0xffffu);
}

// ---------------- CSR build ----------------
__global__ __launch_bounds__(256) void csr_hist(
    const int* __restrict__ col, int* __restrict__ deg)
{
    int e = blockIdx.x * 256 + threadIdx.x;
    atomicAdd(&deg[col[e]], 1);
}

__global__ __launch_bounds__(256) void csr_scan(
    const int* __restrict__ deg, int* __restrict__ offsets,
    int* __restrict__ cursor)
{
    __shared__ int sums[256];
    const int t = threadIdx.x;
    const int CH = 79;
    int base = t * CH;
    int local = 0;
    for (int i = 0; i < CH; ++i) {
        int idx = base + i;
        if (idx < N_NODES) local += deg[idx];
    }
    sums[t] = local;
    __syncthreads();
    for (int off = 1; off < 256; off <<= 1) {
        int v = (t >= off) ? sums[t - off] : 0;
        __syncthreads();
        sums[t] += v;
        __syncthreads();
    }
    int run = (t > 0) ? sums[t - 1] : 0;
    for (int i = 0; i < CH; ++i) {
        int idx = base + i;
        if (idx < N_NODES) {
            offsets[idx] = run;
            cursor[idx] = run;
            run += deg[idx];
        }
    }
}

__global__ __launch_bounds__(256) void csr_fill(
    const int* __restrict__ col, int* __restrict__ cursor,
    int* __restrict__ eid)
{
    int e = blockIdx.x * 256 + threadIdx.x;
    int pos = atomicAdd(&cursor[col[e]], 1);
    eid[pos] = e;
}

__global__ __launch_bounds__(256) void ghist(
    const int* __restrict__ batch, int* __restrict__ gdeg)
{
    int n = blockIdx.x * 256 + threadIdx.x;
    if (n < N_NODES) atomicAdd(&gdeg[batch[n]], 1);
}

__global__ __launch_bounds__(128) void gscan(
    const int* __restrict__ gdeg, int* __restrict__ goff)
{
    __shared__ int s[128];
    int t = threadIdx.x;
    int d = gdeg[t];
    s[t] = d;
    __syncthreads();
    for (int off = 1; off < 128; off <<= 1) {
        int v = (t >= off) ? s[t - off] : 0;
        __syncthreads();
        s[t] += v;
        __syncthreads();
    }
    goff[t] = s[t] - d;
    if (t == 127) goff[128] = s[127];
}

// ---------------- W fragment pre-packs ----------------
__global__ __launch_bounds__(64) void wfrag_build(
    const float* __restrict__ W_convs, ushort_t* __restrict__ wfrag)
{
    const int c = blockIdx.x, t = blockIdx.y, l = blockIdx.z;
    const int lane = threadIdx.x;
    const int k0 = c * 32 + (lane >> 4) * 8;
    const int n  = t * 16 + (lane & 15);
    ushort_t* dst = wfrag + (size_t)l * WFRAG_USHORT_PER_LAYER
                  + ((size_t)(c * NTILES + t) * 64 + lane) * 8;
    const float* Wl = W_convs + (size_t)l * HID * HID;
    #pragma unroll
    for (int j = 0; j < 8; ++j) {
        int k = k0 + j;
        float v = (k < HID && n < HID) ? Wl[(long)k * HID + n] : 0.f;
        dst[j] = f2bf(v);
    }
}

__global__ __launch_bounds__(64) void wfrag2_build(
    const float* __restrict__ W_e2n, ushort_t* __restrict__ wfrag2)
{
    const int c = blockIdx.x, t = blockIdx.y;
    const int lane = threadIdx.x;
    const int k0 = c * 32 + (lane >> 4) * 8;
    const int n  = t * 16 + (lane & 15);
    ushort_t* dst = wfrag2 + ((size_t)(c * NTILES + t) * 64 + lane) * 8;
    #pragma unroll
    for (int j = 0; j < 8; ++j) {
        int k = k0 + j;
        float v = (k < F_NODE + HID && n < HID) ? W_e2n[(long)k * HID + n] : 0.f;
        dst[j] = f2bf(v);
    }
}

// W2 (= W_init rows 64..79) as ONE 16x16x32 B-chunk
__global__ __launch_bounds__(64) void w2frag_build(
    const float* __restrict__ W2, ushort_t* __restrict__ w2frag)
{
    const int t = blockIdx.x;
    const int lane = threadIdx.x;
    const int k0 = (lane >> 4) * 8;
    const int n  = t * 16 + (lane & 15);
    ushort_t* dst = w2frag + ((size_t)t * 64 + lane) * 8;
    #pragma unroll
    for (int j = 0; j < 8; ++j) {
        int k = k0 + j;
        float v = (k < F_EDGE && n < HID) ? W2[(long)k * HID + n] : 0.f;
        dst[j] = f2bf(v);
    }
}

// ---------------- kernels ----------------

// K1: xW1b[n][c] = bf16(b_init[c] + x[n] @ W_init[0:64]);  stride HID
__global__ __launch_bounds__(256) void node_init_gemm(
    const float* __restrict__ x, const float* __restrict__ W_init,
    const float* __restrict__ b_init, ushort_t* __restrict__ xW1b)
{
    __shared__ float xs[16 * 64];
    const int tid = threadIdx.x;
    const long n0 = (long)blockIdx.x * 16;
    for (int i = tid; i < 16 * 64; i += 256) xs[i] = x[n0 * 64 + i];
    __syncthreads();
    const int nl = tid >> 4, ct = tid & 15;
    for (int q = 0; q < 19; ++q) {
        int c = ct + 16 * q;
        if (c < HID) {
            float acc = b_init[c];
            #pragma unroll 8
            for (int k = 0; k < 64; ++k)
                acc = fmaf(xs[nl * 64 + k], W_init[(long)k * HID + c], acc);
            xW1b[(n0 + nl) * HID + c] = f2bf(acc);
        }
    }
}

// Phase-0 helper for 512-thr edge_update: wave quarter-tiles of P = EA @ W2.
__device__ __forceinline__ void p_phase8(
    ushort_t* At, const float* __restrict__ edge_attr,
    const ushort_t* __restrict__ w2frag, long e0,
    int wave, int quad, int m, int lane)
{
    const int mtp = wave >> 2;
    const int nt0p = (wave & 3) * 5;
    short8 a_ea;
    {
        union { uint4 u4; short8 s8; } af;
        if (quad < 2) {
            const float* eap = edge_attr + (e0 + mtp * 16 + m) * 16 + quad * 8;
            float4 v0 = *(const float4*)eap;
            float4 v1 = *(const float4*)(eap + 4);
            af.u4.x = fpack(v0.x, v0.y); af.u4.y = fpack(v0.z, v0.w);
            af.u4.z = fpack(v1.x, v1.y); af.u4.w = fpack(v1.z, v1.w);
        } else {
            af.u4.x = 0; af.u4.y = 0; af.u4.z = 0; af.u4.w = 0;
        }
        a_ea = af.s8;
    }
    #pragma unroll
    for (int t = 0; t < 5; ++t) {
        int nt = nt0p + t;
        if (nt >= 19) continue;   // pad tile
        short8 b = *(const short8*)(w2frag + ((size_t)nt * 64 + lane) * 8);
        int c = nt * 16 + m;
        f32x4 pc = (f32x4){0.f, 0.f, 0.f, 0.f};
        pc = __builtin_amdgcn_mfma_f32_16x16x32_bf16(a_ea, b, pc, 0, 0, 0);
        #pragma unroll
        for (int r = 0; r < 4; ++r)
            At[(mtp * 16 + quad * 4 + r) * ATS + c] = f2bf(pc[r]);
    }
}

// Fused conv layer, 32-edge blocks, 256 thr / 4 waves (proven R2 shape,
// 60 VGPR -- MUST stay <=64: crossing 64 halves waves/SIMD, R4 lesson).
// Only change vs R2: ATS 328->344 (bank-conflict fix, see #define).
template<bool UPDATE>
__global__ __launch_bounds__(256) void fused_conv(
    ushort_t* h, const ushort_t* __restrict__ Sb,
    const ushort_t* __restrict__ xW1b, const float* __restrict__ edge_attr,
    const int* __restrict__ row, const ushort_t* __restrict__ w2frag,
    const ushort_t* __restrict__ wfrag_l)
{
    __shared__ ushort_t At[32 * ATS];   // 22016 B
    __shared__ int rows[32];
    const int tid = threadIdx.x;
    const int wave = tid >> 6, lane = tid & 63;
    const int quad = lane >> 4, m = lane & 15;
    const long e0 = (long)blockIdx.x * 32;
    if (tid < 32) rows[tid] = row[e0 + tid];

    // ---- phase 0: P = EA @ W2 ----
    {
        short8 a_ea[2];
        #pragma unroll
        for (int mt = 0; mt < 2; ++mt) {
            union { uint4 u4; short8 s8; } af;
            if (quad < 2) {
                const float* eap = edge_attr + (e0 + mt * 16 + m) * 16 + quad * 8;
                float4 v0 = *(const float4*)eap;
                float4 v1 = *(const float4*)(eap + 4);
                af.u4.x = fpack(v0.x, v0.y); af.u4.y = fpack(v0.z, v0.w);
                af.u4.z = fpack(v1.x, v1.y); af.u4.w = fpack(v1.z, v1.w);
            } else {
                af.u4.x = 0; af.u4.y = 0; af.u4.z = 0; af.u4.w = 0;
            }
            a_ea[mt] = af.s8;
        }
        const int nt0 = wave * 5;
        #pragma unroll
        for (int t = 0; t < 5; ++t) {
            short8 b = *(const short8*)(w2frag + ((size_t)(nt0 + t) * 64 + lane) * 8);
            int c = (nt0 + t) * 16 + m;
            #pragma unroll
            for (int mt = 0; mt < 2; ++mt) {
                f32x4 pc = (f32x4){0.f, 0.f, 0.f, 0.f};
                pc = __builtin_amdgcn_mfma_f32_16x16x32_bf16(a_ea[mt], b, pc, 0, 0, 0);
                #pragma unroll
                for (int r = 0; r < 4; ++r)
                    At[(mt * 16 + quad * 4 + r) * ATS + c] = f2bf(pc[r]);
            }
        }
    }
    __syncthreads();   // P complete (+ rows)

    // ---- phase 1: edge update into At (16 pairs x 80 col-groups) ----
    for (int i = tid; i < 16 * 80; i += 256) {
        int p = i / 80, g = i % 80;
        int c0 = 4 * g;
        int la = 2 * p, lb = 2 * p + 1;
        uint2 oa, ob;
        if (g < 75) {
            long Ea = e0 + la, Eb = e0 + lb;
            int ra = rows[la], rb = rows[lb];
            uint2 xa = *(const uint2*)&xW1b[(long)ra * HID + c0];
            uint2 xb = *(const uint2*)&xW1b[(long)rb * HID + c0];
            uint2 pa = *(const uint2*)&At[la * ATS + c0];
            uint2 pb = *(const uint2*)&At[lb * ATS + c0];
            f32x2 h0a0 = pmax0(bfpair(xa.x) + bfpair(pa.x));
            f32x2 h0a1 = pmax0(bfpair(xa.y) + bfpair(pa.y));
            f32x2 h0b0 = pmax0(bfpair(xb.x) + bfpair(pb.x));
            f32x2 h0b1 = pmax0(bfpair(xb.y) + bfpair(pb.y));
            if (UPDATE) {
                uint2 wa = *(const uint2*)&h[Ea * HP + c0];
                uint2 wb = *(const uint2*)&h[Eb * HP + c0];
                uint2 sa = *(const uint2*)&Sb[(long)ra * HID + c0];
                uint2 sb = *(const uint2*)&Sb[(long)rb * HID + c0];
                oa.x = fpack2(pmax0(bfpair(sa.x) - bfpair(wb.x) + h0a0));
                oa.y = fpack2(pmax0(bfpair(sa.y) - bfpair(wb.y) + h0a1));
                ob.x = fpack2(pmax0(bfpair(sb.x) - bfpair(wa.x) + h0b0));
                ob.y = fpack2(pmax0(bfpair(sb.y) - bfpair(wa.y) + h0b1));
            } else {
                oa.x = fpack2(h0a0); oa.y = fpack2(h0a1);
                ob.x = fpack2(h0b0); ob.y = fpack2(h0b1);
            }
        } else {
            oa.x = 0; oa.y = 0;   // K-pad cols 300..319
            ob = oa;
        }
        *(uint2*)&At[la * ATS + c0] = oa;
        *(uint2*)&At[lb * ATS + c0] = ob;
    }
    __syncthreads();   // A tile complete; all h reads done

    // ---- phase 2: main MFMA ----
    const int nt0 = wave * 5;
    f32x4 acc[5][2];
    #pragma unroll
    for (int t = 0; t < 5; ++t)
        #pragma unroll
        for (int mt = 0; mt < 2; ++mt)
            acc[t][mt] = (f32x4){0.f, 0.f, 0.f, 0.f};

    for (int c = 0; c < 10; ++c) {
        short8 a[2];
        #pragma unroll
        for (int mt = 0; mt < 2; ++mt)
            a[mt] = *(const short8*)&At[(mt * 16 + m) * ATS + c * 32 + quad * 8];
        #pragma unroll
        for (int t = 0; t < 5; ++t) {
            short8 b = *(const short8*)(wfrag_l
                + ((size_t)(c * NTILES + nt0 + t) * 64 + lane) * 8);
            #pragma unroll
            for (int mt = 0; mt < 2; ++mt)
                acc[t][mt] = __builtin_amdgcn_mfma_f32_16x16x32_bf16(
                    a[mt], b, acc[t][mt], 0, 0, 0);
        }
    }
    #pragma unroll
    for (int t = 0; t < 5; ++t) {
        int col = (nt0 + t) * 16 + m;
        if (col >= HID) continue;
        #pragma unroll
        for (int mt = 0; mt < 2; ++mt) {
            long rbase = (e0 + mt * 16 + quad * 4) * HP + col;
            #pragma unroll
            for (int r = 0; r < 4; ++r)
                h[rbase + (long)r * HP] = f2bf(acc[t][mt][r]);
        }
    }
}

// Final edge update: 32 edges/blk, 512 thr / 8 waves, issue-early pipeline.
__global__ __launch_bounds__(512) void edge_update_mfma(
    ushort_t* h, const ushort_t* __restrict__ Sb,
    const ushort_t* __restrict__ xW1b, const float* __restrict__ edge_attr,
    const int* __restrict__ row, const ushort_t* __restrict__ w2frag)
{
    __shared__ ushort_t Pt[32 * ATS];
    const int tid = threadIdx.x;
    const int wave = tid >> 6, lane = tid & 63;
    const int quad = lane >> 4, m = lane & 15;
    const long e0 = (long)blockIdx.x * 32;

    auto issue = [&](int k, uint2& xa, uint2& xb, uint2& wa, uint2& wb,
                     uint2& sa, uint2& sb, int& la, int& lb, int& g, bool& v) {
        int i = tid + (k << 9);
        v = i < 16 * 75;
        if (v) {
            int p = i / 75; g = i % 75;
            la = 2 * p; lb = la + 1;
            int c0 = 4 * g;
            int ra = row[e0 + la], rb = row[e0 + lb];
            xa = *(const uint2*)&xW1b[(long)ra * HID + c0];
            xb = *(const uint2*)&xW1b[(long)rb * HID + c0];
            wa = *(const uint2*)&h[(e0 + la) * HP + c0];
            wb = *(const uint2*)&h[(e0 + lb) * HP + c0];
            sa = *(const uint2*)&Sb[(long)ra * HID + c0];
            sb = *(const uint2*)&Sb[(long)rb * HID + c0];
        }
    };

    uint2 xa0, xb0, wa0, wb0, sa0, sb0;
    int la0 = 0, lb0 = 0, g0 = 0; bool v0 = false;
    issue(0, xa0, xb0, wa0, wb0, sa0, sb0, la0, lb0, g0, v0);   // EARLY

    p_phase8(Pt, edge_attr, w2frag, e0, wave, quad, m, lane);
    __syncthreads();

    #pragma unroll
    for (int k = 0; k < 3; ++k) {
        uint2 xa1, xb1, wa1, wb1, sa1, sb1;
        int la1 = 0, lb1 = 0, g1 = 0; bool v1 = false;
        if (k < 2)
            issue(k + 1, xa1, xb1, wa1, wb1, sa1, sb1, la1, lb1, g1, v1);
        if (v0) {
            int c0 = 4 * g0;
            uint2 pa = *(const uint2*)&Pt[la0 * ATS + c0];
            uint2 pb = *(const uint2*)&Pt[lb0 * ATS + c0];
            f32x2 h0a0 = pmax0(bfpair(xa0.x) + bfpair(pa.x));
            f32x2 h0a1 = pmax0(bfpair(xa0.y) + bfpair(pa.y));
            f32x2 h0b0 = pmax0(bfpair(xb0.x) + bfpair(pb.x));
            f32x2 h0b1 = pmax0(bfpair(xb0.y) + bfpair(pb.y));
            uint2 oa, ob;
            oa.x = fpack2(pmax0(bfpair(sa0.x) - bfpair(wb0.x) + h0a0));
            oa.y = fpack2(pmax0(bfpair(sa0.y) - bfpair(wb0.y) + h0a1));
            ob.x = fpack2(pmax0(bfpair(sb0.x) - bfpair(wa0.x) + h0b0));
            ob.y = fpack2(pmax0(bfpair(sb0.y) - bfpair(wa0.y) + h0b1));
            *(uint2*)&h[(e0 + la0) * HP + c0] = oa;
            *(uint2*)&h[(e0 + lb0) * HP + c0] = ob;
        }
        if (k < 2) {
            xa0 = xa1; xb0 = xb1; wa0 = wa1; wb0 = wb1;
            sa0 = sa1; sb0 = sb1; la0 = la1; lb0 = lb1; g0 = g1; v0 = v1;
        }
    }
}

// K4: Sb[n][:] = bf16( bias[:] + segsum );  stride HID. 4-deep MLP.
__global__ __launch_bounds__(256) void gather_sum(
    const ushort_t* __restrict__ src, const int* __restrict__ offsets,
    const int* __restrict__ ends, const int* __restrict__ eid,
    const float* __restrict__ bias, ushort_t* __restrict__ Sb)
{
    long idx = (long)blockIdx.x * 256 + threadIdx.x;
    if (idx >= (long)N_NODES * 75) return;
    int n = (int)(idx / 75);
    int g = (int)(idx % 75);
    int beg = offsets[n], end = ends[n];
    f32x2 A0 = {0.f, 0.f}, A1 = {0.f, 0.f};
    f32x2 B0 = {0.f, 0.f}, B1 = {0.f, 0.f};
    f32x2 C0 = {0.f, 0.f}, C1 = {0.f, 0.f};
    f32x2 D0 = {0.f, 0.f}, D1 = {0.f, 0.f};
    int j = beg;
    for (; j + 3 < end; j += 4) {
        int ea = eid[j], eb = eid[j + 1], ec = eid[j + 2], ed = eid[j + 3];
        uint2 va = ((const uint2*)src)[(long)ea * (HP / 4) + g];
        uint2 vb = ((const uint2*)src)[(long)eb * (HP / 4) + g];
        uint2 vc = ((const uint2*)src)[(long)ec * (HP / 4) + g];
        uint2 vd = ((const uint2*)src)[(long)ed * (HP / 4) + g];
        A0 += bfpair(va.x); A1 += bfpair(va.y);
        B0 += bfpair(vb.x); B1 += bfpair(vb.y);
        C0 += bfpair(vc.x); C1 += bfpair(vc.y);
        D0 += bfpair(vd.x); D1 += bfpair(vd.y);
    }
    for (; j < end; ++j) {
        int ea = eid[j];
        uint2 va = ((const uint2*)src)[(long)ea * (HP / 4) + g];
        A0 += bfpair(va.x); A1 += bfpair(va.y);
    }
    float4 bv = *(const float4*)&bias[4 * g];
    f32x2 bv0 = {bv.x, bv.y}, bv1 = {bv.z, bv.w};
    uint2 o;
    o.x = fpack2((A0 + B0) + (C0 + D0) + bv0);
    o.y = fpack2((A1 + B1) + (C1 + D1) + bv1);
    *(uint2*)&Sb[(long)n * HID + 4 * g] = o;
}

// K4b: final gather -> bf16 into Ab cols 64..363. 4-deep MLP.
__global__ __launch_bounds__(256) void gather_ab(
    const ushort_t* __restrict__ src, const int* __restrict__ offsets,
    const int* __restrict__ ends, const int* __restrict__ eid,
    ushort_t* __restrict__ Ab)
{
    long idx = (long)blockIdx.x * 256 + threadIdx.x;
    if (idx >= (long)N_NODES * 75) return;
    int n = (int)(idx / 75);
    int g = (int)(idx % 75);
    int beg = offsets[n], end = ends[n];
    f32x2 A0 = {0.f, 0.f}, A1 = {0.f, 0.f};
    f32x2 B0 = {0.f, 0.f}, B1 = {0.f, 0.f};
    f32x2 C0 = {0.f, 0.f}, C1 = {0.f, 0.f};
    f32x2 D0 = {0.f, 0.f}, D1 = {0.f, 0.f};
    int j = beg;
    for (; j + 3 < end; j += 4) {
        int ea = eid[j], eb = eid[j + 1], ec = eid[j + 2], ed = eid[j + 3];
        uint2 va = ((const uint2*)src)[(long)ea * (HP / 4) + g];
        uint2 vb = ((const uint2*)src)[(long)eb * (HP / 4) + g];
        uint2 vc = ((const uint2*)src)[(long)ec * (HP / 4) + g];
        uint2 vd = ((const uint2*)src)[(long)ed * (HP / 4) + g];
        A0 += bfpair(va.x); A1 += bfpair(va.y);
        B0 += bfpair(vb.x); B1 += bfpair(vb.y);
        C0 += bfpair(vc.x); C1 += bfpair(vc.y);
        D0 += bfpair(vd.x); D1 += bfpair(vd.y);
    }
    for (; j < end; ++j) {
        int ea = eid[j];
        uint2 va = ((const uint2*)src)[(long)ea * (HP / 4) + g];
        A0 += bfpair(va.x); A1 += bfpair(va.y);
    }
    uint2 o;
    o.x = fpack2((A0 + B0) + (C0 + D0));
    o.y = fpack2((A1 + B1) + (C1 + D1));
    *(uint2*)&Ab[(long)n * KE2N + 64 + 4 * g] = o;
}

__global__ __launch_bounds__(256) void x_fill(
    const float* __restrict__ x, ushort_t* __restrict__ Ab)
{
    long idx = (long)blockIdx.x * 256 + threadIdx.x;
    if (idx >= (long)N_NODES * 21) return;
    int n = (int)(idx / 21);
    int q = (int)(idx % 21);
    if (q < 16) {
        float4 v = *(const float4*)&x[(long)n * 64 + 4 * q];
        uint2 o;
        o.x = fpack(v.x, v.y);
        o.y = fpack(v.z, v.w);
        *(uint2*)&Ab[(long)n * KE2N + 4 * q] = o;
    } else {
        uint2 o; o.x = 0; o.y = 0;
        *(uint2*)&Ab[(long)n * KE2N + 364 + 4 * (q - 16)] = o;
    }
}

// K7: hn = relu(Ab @ W_e2n + b).  32 rows/block (20000 = 625*32 exactly,
// no tail clamps); doubles block count vs 64-row (313 -> 625) for the
// latency-exposed small grid.
__global__ __launch_bounds__(256) void e2n_mfma(
    const ushort_t* __restrict__ Ab, const ushort_t* __restrict__ wfrag2,
    const float* __restrict__ b_e2n, float* __restrict__ hn)
{
    const int tid = threadIdx.x;
    const int wave = tid >> 6, lane = tid & 63;
    const int quad = lane >> 4, m = lane & 15;
    const long n0 = (long)blockIdx.x * 32;
    const int nt0 = wave * 5;

    f32x4 acc[5][2];
    #pragma unroll
    for (int t = 0; t < 5; ++t)
        #pragma unroll
        for (int mt = 0; mt < 2; ++mt)
            acc[t][mt] = (f32x4){0.f, 0.f, 0.f, 0.f};

    for (int c = 0; c < 12; ++c) {
        short8 a[2];
        #pragma unroll
        for (int mt = 0; mt < 2; ++mt) {
            long r = n0 + mt * 16 + m;
            a[mt] = *(const short8*)(Ab + r * KE2N + c * 32 + quad * 8);
        }
        #pragma unroll
        for (int t = 0; t < 5; ++t) {
            short8 b = *(const short8*)(wfrag2
                + ((size_t)(c * NTILES + nt0 + t) * 64 + lane) * 8);
            #pragma unroll
            for (int mt = 0; mt < 2; ++mt)
                acc[t][mt] = __builtin_amdgcn_mfma_f32_16x16x32_bf16(
                    a[mt], b, acc[t][mt], 0, 0, 0);
        }
    }

    #pragma unroll
    for (int t = 0; t < 5; ++t) {
        int col = (nt0 + t) * 16 + m;
        if (col >= HID) continue;
        float bias = b_e2n[col];
        #pragma unroll
        for (int mt = 0; mt < 2; ++mt) {
            long rw = n0 + mt * 16 + quad * 4;
            #pragma unroll
            for (int r = 0; r < 4; ++r)
                hn[(rw + r) * HP + col] = fmaxf(acc[t][mt][r] + bias, 0.f);
        }
    }
}

__global__ __launch_bounds__(256) void pool_graph(
    const float* __restrict__ hn, const int* __restrict__ goff,
    float* __restrict__ pooled)
{
    int g = blockIdx.x;
    int beg = goff[g], end = goff[g + 1];
    for (int c = threadIdx.x; c < HID; c += 256) {
        float acc = 0.f;
        for (int n = beg; n < end; ++n)
            acc += hn[(long)n * HP + c];
        pooled[(long)g * HID + c] = acc;
    }
}

__global__ __launch_bounds__(64) void ffn_out(
    const float* __restrict__ pooled, const float* __restrict__ W_ffn,
    const float* __restrict__ b_ffn, float* __restrict__ out)
{
    int g = blockIdx.x;
    int lane = threadIdx.x;
    float s = 0.f;
    for (int c = lane; c < HID; c += 64)
        s += pooled[(long)g * HID + c] * W_ffn[c];
    #pragma unroll
    for (int off = 32; off > 0; off >>= 1)
        s += __shfl_down(s, off, 64);
    if (lane == 0) out[g] = s + b_ffn[0];
}

extern "C" void kernel_launch(void* const* d_in, const int* in_sizes, int n_in,
                              void* d_out, int out_size, void* d_ws, size_t ws_size,
                              hipStream_t stream) {
    const float* x         = (const float*)d_in[0];
    const float* edge_attr = (const float*)d_in[1];
    const int*   edge_index= (const int*)d_in[2];
    const int*   batch     = (const int*)d_in[3];
    const float* W_init    = (const float*)d_in[4];
    const float* b_init    = (const float*)d_in[5];
    const float* W_convs   = (const float*)d_in[6];
    const float* b_convs   = (const float*)d_in[7];
    const float* W_e2n     = (const float*)d_in[8];
    const float* b_e2n     = (const float*)d_in[9];
    const float* W_ffn     = (const float*)d_in[10];
    const float* b_ffn     = (const float*)d_in[11];
    float* out = (float*)d_out;

    const int* row = edge_index;
    const int* col = edge_index + N_EDGES;
    const float* W2 = W_init + (size_t)F_NODE * HID;

    // Workspace (~225 MB)
    const size_t need = (size_t)N_EDGES * HP * 2
                      + (size_t)N_NODES * HID * 2
                      + (size_t)N_NODES * KE2N * 2
                      + (size_t)N_GRAPHS * HID * 4
                      + (size_t)N_NODES * 4 * 2 + (size_t)N_EDGES * 4
                      + (size_t)DEPTH * WFRAG_USHORT_PER_LAYER * 2
                      + (size_t)WE2NFRAG_USHORT * 2
                      + (size_t)W2FRAG_USHORT * 2
                      + (size_t)(N_GRAPHS + 1 + N_GRAPHS) * 4 + 32768;
    if (ws_size < need) return;

    char* p = (char*)d_ws;
    auto take = [&](size_t bytes) {
        char* q = p;
        p += (bytes + 255) & ~(size_t)255;
        return q;
    };
    ushort_t* h       = (ushort_t*)take((size_t)N_EDGES * HP * 2);
    ushort_t* Sb      = (ushort_t*)take((size_t)N_NODES * HID * 2);
    ushort_t* Ab      = (ushort_t*)take((size_t)N_NODES * KE2N * 2);
    float*    pooled  = (float*)take((size_t)N_GRAPHS * HID * 4);
    int*      cursor  = (int*)take((size_t)N_NODES * 4);
    int*      offsets = (int*)take((size_t)N_NODES * 4);
    int*      eid     = (int*)take((size_t)N_EDGES * 4);
    ushort_t* wfrag   = (ushort_t*)take((size_t)DEPTH * WFRAG_USHORT_PER_LAYER * 2);
    ushort_t* wfrag2  = (ushort_t*)take((size_t)WE2NFRAG_USHORT * 2);
    ushort_t* w2frag  = (ushort_t*)take((size_t)W2FRAG_USHORT * 2);
    int*      gdeg    = (int*)take((size_t)N_GRAPHS * 4);
    int*      goff    = (int*)take((size_t)(N_GRAPHS + 1) * 4);

    ushort_t* xW1b = Ab;        // alias: xW1b dead before x_fill writes Ab
    float*    hn   = (float*)h; // alias: h dead after gather_ab

    // CSR + graph-offset build
    hipMemsetAsync(cursor, 0, (size_t)N_NODES * 4, stream);
    hipMemsetAsync(gdeg, 0, (size_t)N_GRAPHS * 4, stream);
    csr_hist<<<N_EDGES / 256, 256, 0, stream>>>(col, cursor);
    csr_scan<<<1, 256, 0, stream>>>(cursor, offsets, cursor);
    csr_fill<<<N_EDGES / 256, 256, 0, stream>>>(col, cursor, eid);
    ghist<<<(N_NODES + 255) / 256, 256, 0, stream>>>(batch, gdeg);
    gscan<<<1, 128, 0, stream>>>(gdeg, goff);

    wfrag_build<<<dim3(10, NTILES, DEPTH), 64, 0, stream>>>(W_convs, wfrag);
    wfrag2_build<<<dim3(12, NTILES, 1), 64, 0, stream>>>(W_e2n, wfrag2);
    w2frag_build<<<NTILES, 64, 0, stream>>>(W2, w2frag);

    node_init_gemm<<<N_NODES / 16, 256, 0, stream>>>(x, W_init, b_init, xW1b);

    const int GS_GRID = ((N_NODES * 75) + 255) / 256;

    // layer 0
    fused_conv<false><<<N_EDGES / 32, 256, 0, stream>>>(
        h, Sb, xW1b, edge_attr, row, w2frag, wfrag);
    gather_sum<<<GS_GRID, 256, 0, stream>>>(
        h, offsets, cursor, eid, b_convs + 0 * HID, Sb);
    // layers 1,2
    fused_conv<true><<<N_EDGES / 32, 256, 0, stream>>>(
        h, Sb, xW1b, edge_attr, row, w2frag,
        wfrag + 1 * (size_t)WFRAG_USHORT_PER_LAYER);
    gather_sum<<<GS_GRID, 256, 0, stream>>>(
        h, offsets, cursor, eid, b_convs + 1 * HID, Sb);
    fused_conv<true><<<N_EDGES / 32, 256, 0, stream>>>(
        h, Sb, xW1b, edge_attr, row, w2frag,
        wfrag + 2 * (size_t)WFRAG_USHORT_PER_LAYER);
    gather_sum<<<GS_GRID, 256, 0, stream>>>(
        h, offsets, cursor, eid, b_convs + 2 * HID, Sb);
    // final update
    edge_update_mfma<<<N_EDGES / 32, 512, 0, stream>>>(
        h, Sb, xW1b, edge_attr, row, w2frag);

    // ---- e2n path ----
    x_fill<<<((N_NODES * 21) + 255) / 256, 256, 0, stream>>>(x, Ab);
    gather_ab<<<GS_GRID, 256, 0, stream>>>(h, offsets, cursor, eid, Ab);
    e2n_mfma<<<N_NODES / 32, 256, 0, stream>>>(Ab, wfrag2, b_e2n, hn);
    pool_graph<<<N_GRAPHS, 256, 0, stream>>>(hn, goff, pooled);
    ffn_out<<<N_GRAPHS, 64, 0, stream>>>(pooled, W_ffn, b_ffn, out);
}